// Round 1
// baseline (339.079 us; speedup 1.0000x reference)
//
#include <hip/hip_runtime.h>
#include <hip/hip_bf16.h>

// Problem constants (fixed by the reference harness)
#define NN 65536            // total nodes
#define NE (NN * 16)        // total edges = 1,048,576
#define NG 32               // graphs
#define MAXD 64             // ELL slots per node (max in-degree ~45 for Poisson(16))

// Workspace layout (bytes)
#define WS_CURSOR 0                         // NN ints        = 262144
#define WS_SUMMED 262144                    // NG*30 floats   = 3840
#define WS_ELL    1048576                   // NN*MAXD ints   = 16 MB
#define WS_ZA     (WS_ELL + NN * MAXD * 4)  // NN*32 f32      = 8 MB
#define WS_ZB     (WS_ZA + NN * 32 * 4)
#define WS_H1     (WS_ZB + NN * 32 * 4)
#define WS_H2     (WS_H1 + NN * 32 * 4)
#define WS_H3     (WS_H2 + NN * 32 * 4)
#define WS_Z4     (WS_H3 + NN * 32 * 4)     // NN f32

// ---------------------------------------------------------------------------
// Build ELL adjacency rows keyed by dst: ell[dst][slot] = src
__global__ __launch_bounds__(256) void k_build(const int* __restrict__ ei,
                                               int* __restrict__ cursor,
                                               int* __restrict__ ell) {
    int e = blockIdx.x * 256 + threadIdx.x;
    int src = ei[e];
    int dst = ei[NE + e];
    int slot = atomicAdd(&cursor[dst], 1);
    if (slot < MAXD) ell[dst * MAXD + slot] = src;
}

// ---------------------------------------------------------------------------
// z1 = feat (N x 128) @ W0 (128 x 32).  64 rows/block, thread = 4 rows x 2 cols.
__global__ __launch_bounds__(256) void k_gemm1(const float* __restrict__ feat,
                                               const float* __restrict__ W0,
                                               float* __restrict__ z1) {
    __shared__ float wl[32 * 132];   // W transposed: wl[c][k], stride 132 (33 float4 -> conflict-friendly)
    __shared__ float hl[64 * 132];   // feat rows: hl[r][k], stride 132
    int tid = threadIdx.x;
    for (int i = tid; i < 128 * 32; i += 256) {
        int k = i >> 5, c = i & 31;
        wl[c * 132 + k] = W0[i];
    }
    int base = blockIdx.x * 64;
    const float* fsrc = feat + (size_t)base * 128;
    #pragma unroll
    for (int v = 0; v < 8; ++v) {
        int flat = v * 1024 + tid * 4;
        int rr = flat >> 7, kk = flat & 127;
        *(float4*)&hl[rr * 132 + kk] = *(const float4*)&fsrc[flat];
    }
    __syncthreads();
    int cg = tid & 15, rg = tid >> 4;
    int c0 = cg * 2, r0 = rg * 4;
    float acc[4][2] = {};
    #pragma unroll 2
    for (int k = 0; k < 128; k += 4) {
        float4 wa = *(const float4*)&wl[c0 * 132 + k];
        float4 wb = *(const float4*)&wl[(c0 + 1) * 132 + k];
        #pragma unroll
        for (int rr = 0; rr < 4; ++rr) {
            float4 hv = *(const float4*)&hl[(r0 + rr) * 132 + k];
            acc[rr][0] += hv.x * wa.x + hv.y * wa.y + hv.z * wa.z + hv.w * wa.w;
            acc[rr][1] += hv.x * wb.x + hv.y * wb.y + hv.z * wb.z + hv.w * wb.w;
        }
    }
    #pragma unroll
    for (int rr = 0; rr < 4; ++rr) {
        int d = base + r0 + rr;
        z1[d * 32 + c0]     = acc[rr][0];
        z1[d * 32 + c0 + 1] = acc[rr][1];
    }
}

// ---------------------------------------------------------------------------
// Fused: agg = A*zin;  h = tanh((agg + zin + b)/deg);  znext = h @ Wn (32x32)
__global__ __launch_bounds__(256) void k_layer(const int* __restrict__ cursor,
                                               const int* __restrict__ ell,
                                               const float* __restrict__ zin,
                                               const float* __restrict__ degs,
                                               const float* __restrict__ bias,
                                               const float* __restrict__ Wn,
                                               float* __restrict__ hout,
                                               float* __restrict__ znext) {
    __shared__ float wl[1024];
    __shared__ float hl[8 * 33];
    int tid = threadIdx.x;
    for (int i = tid; i < 1024; i += 256) wl[i] = Wn[i];
    int r = tid >> 5, c = tid & 31;
    int d = blockIdx.x * 8 + r;
    int cnt = cursor[d]; if (cnt > MAXD) cnt = MAXD;
    const int* row = ell + (size_t)d * MAXD;
    // prefetch indices into registers; distribute via shuffle (breaks load-load dep chain)
    int i0 = row[c];
    int i1 = row[32 + c];
    float acc = 0.f;
    int m = cnt < 32 ? cnt : 32;
    for (int j = 0; j < m; ++j) {
        int s = __shfl(i0, j, 32);
        acc += zin[s * 32 + c];
    }
    for (int j = 32; j < cnt; ++j) {
        int s = __shfl(i1, j - 32, 32);
        acc += zin[s * 32 + c];
    }
    float val = tanhf((acc + zin[d * 32 + c] + bias[c]) / degs[d]);
    hout[d * 32 + c] = val;
    hl[r * 33 + c] = val;
    __syncthreads();
    float z = 0.f;
    #pragma unroll
    for (int k = 0; k < 32; ++k) z += hl[r * 33 + k] * wl[k * 32 + c];
    znext[d * 32 + c] = z;
}

// ---------------------------------------------------------------------------
// Layer 3 variant: znext is 1-wide (z4 = h3 @ W3), done with a shuffle reduce.
__global__ __launch_bounds__(256) void k_layer3(const int* __restrict__ cursor,
                                                const int* __restrict__ ell,
                                                const float* __restrict__ zin,
                                                const float* __restrict__ degs,
                                                const float* __restrict__ bias,
                                                const float* __restrict__ W3,
                                                float* __restrict__ hout,
                                                float* __restrict__ z4) {
    int tid = threadIdx.x;
    int r = tid >> 5, c = tid & 31;
    int d = blockIdx.x * 8 + r;
    int cnt = cursor[d]; if (cnt > MAXD) cnt = MAXD;
    const int* row = ell + (size_t)d * MAXD;
    int i0 = row[c];
    int i1 = row[32 + c];
    float acc = 0.f;
    int m = cnt < 32 ? cnt : 32;
    for (int j = 0; j < m; ++j) {
        int s = __shfl(i0, j, 32);
        acc += zin[s * 32 + c];
    }
    for (int j = 32; j < cnt; ++j) {
        int s = __shfl(i1, j - 32, 32);
        acc += zin[s * 32 + c];
    }
    float val = tanhf((acc + zin[d * 32 + c] + bias[c]) / degs[d]);
    hout[d * 32 + c] = val;
    float v = val * W3[c];
    #pragma unroll
    for (int off = 16; off; off >>= 1) v += __shfl_xor(v, off, 32);
    if (c == 0) z4[d] = v;
}

// ---------------------------------------------------------------------------
// Fused: layer-4 gather (1-wide) -> h4; msg=[h1 h2 h3 h4]; phi=relu(msg@phiW+b);
// per-graph partial sum -> one atomicAdd set per block.
__global__ __launch_bounds__(256) void k_phi(const int* __restrict__ cursor,
                                             const int* __restrict__ ell,
                                             const float* __restrict__ z4,
                                             const float* __restrict__ degs,
                                             const float* __restrict__ b3,
                                             const float* __restrict__ h1,
                                             const float* __restrict__ h2,
                                             const float* __restrict__ h3,
                                             const float* __restrict__ phiW,
                                             const float* __restrict__ phib,
                                             float* __restrict__ summed) {
    __shared__ float pl[97 * 30];
    __shared__ float ml[8 * 97];
    __shared__ float part[4][32];
    int tid = threadIdx.x;
    for (int i = tid; i < 97 * 30; i += 256) pl[i] = phiW[i];
    int r = tid >> 5, c = tid & 31;
    int d = blockIdx.x * 8 + r;
    int g = d >> 11;
    int cnt = cursor[d]; if (cnt > MAXD) cnt = MAXD;
    const int* row = ell + (size_t)d * MAXD;
    float acc = 0.f;
    for (int j = c; j < cnt; j += 32) acc += z4[row[j]];
    #pragma unroll
    for (int off = 16; off; off >>= 1) acc += __shfl_xor(acc, off, 32);
    float h4 = tanhf((acc + z4[d] + b3[0]) / degs[d]);   // uniform across the 32-lane group
    ml[r * 97 + c]      = h1[d * 32 + c];
    ml[r * 97 + 32 + c] = h2[d * 32 + c];
    ml[r * 97 + 64 + c] = h3[d * 32 + c];
    if (c == 0) ml[r * 97 + 96] = h4;
    __syncthreads();
    float s = 0.f;
    if (c < 30) {
        s = phib[c];
        for (int j = 0; j < 97; ++j) s += ml[r * 97 + j] * pl[j * 30 + c];
        s = fmaxf(s, 0.f);
    }
    s += __shfl_down(s, 32);                 // rows pair-summed within each wave
    int wave = tid >> 6;
    if ((tid & 63) < 32) part[wave][tid & 31] = s;
    __syncthreads();
    if (tid < 32) {
        float tot = part[0][tid] + part[1][tid] + part[2][tid] + part[3][tid];
        if (tid < 30) atomicAdd(&summed[g * 30 + tid], tot);
    }
}

// ---------------------------------------------------------------------------
// out = summed @ rhoW + rhob   (32x30 @ 30x32)
__global__ __launch_bounds__(1024) void k_rho(const float* __restrict__ summed,
                                              const float* __restrict__ rhoW,
                                              const float* __restrict__ rhob,
                                              float* __restrict__ out) {
    int tid = threadIdx.x;
    int b = tid >> 5, o = tid & 31;
    float s = rhob[o];
    #pragma unroll
    for (int k = 0; k < 30; ++k) s += summed[b * 30 + k] * rhoW[k * 32 + o];
    out[tid] = s;
}

// ---------------------------------------------------------------------------
extern "C" void kernel_launch(void* const* d_in, const int* in_sizes, int n_in,
                              void* d_out, int out_size, void* d_ws, size_t ws_size,
                              hipStream_t stream) {
    const float* feat = (const float*)d_in[0];
    const float* degs = (const float*)d_in[1];
    const int*   ei   = (const int*)d_in[2];
    const float* W0   = (const float*)d_in[3];
    const float* b0   = (const float*)d_in[4];
    const float* W1   = (const float*)d_in[5];
    const float* b1   = (const float*)d_in[6];
    const float* W2   = (const float*)d_in[7];
    const float* b2   = (const float*)d_in[8];
    const float* W3   = (const float*)d_in[9];
    const float* b3   = (const float*)d_in[10];
    const float* phiW = (const float*)d_in[11];
    const float* phib = (const float*)d_in[12];
    const float* rhoW = (const float*)d_in[13];
    const float* rhob = (const float*)d_in[14];

    char* ws = (char*)d_ws;
    int*   cursor = (int*)(ws + WS_CURSOR);
    float* summed = (float*)(ws + WS_SUMMED);
    int*   ell    = (int*)(ws + WS_ELL);
    float* za     = (float*)(ws + WS_ZA);
    float* zb     = (float*)(ws + WS_ZB);
    float* h1     = (float*)(ws + WS_H1);
    float* h2     = (float*)(ws + WS_H2);
    float* h3     = (float*)(ws + WS_H3);
    float* z4     = (float*)(ws + WS_Z4);
    float* out    = (float*)d_out;

    // zero cursor + summed (ws is poisoned to 0xAA before every launch)
    hipMemsetAsync(ws, 0, WS_SUMMED + NG * 30 * 4, stream);

    k_build <<<NE / 256, 256, 0, stream>>>(ei, cursor, ell);
    k_gemm1 <<<NN / 64, 256, 0, stream>>>(feat, W0, za);
    k_layer <<<NN / 8, 256, 0, stream>>>(cursor, ell, za, degs, b0, W1, h1, zb);
    k_layer <<<NN / 8, 256, 0, stream>>>(cursor, ell, zb, degs, b1, W2, h2, za);
    k_layer3<<<NN / 8, 256, 0, stream>>>(cursor, ell, za, degs, b2, W3, h3, z4);
    k_phi   <<<NN / 8, 256, 0, stream>>>(cursor, ell, z4, degs, b3, h1, h2, h3, phiW, phib, summed);
    k_rho   <<<1, 1024, 0, stream>>>(summed, rhoW, rhob, out);
}

// Round 2
// 294.744 us; speedup vs baseline: 1.1504x; 1.1504x over previous
//
#include <hip/hip_runtime.h>
#include <hip/hip_bf16.h>

// Problem constants (fixed by the reference harness)
#define NN 65536            // total nodes
#define NE (NN * 16)        // total edges = 1,048,576
#define NG 32               // graphs
#define MAXD 64             // ELL slots per node (max in-degree ~45 for Poisson(16))

// Workspace layout (bytes)
#define WS_CURSOR 0                         // NN ints        = 262144
#define WS_SUMMED 262144                    // NG*30 floats   = 3840
#define WS_ELL    1048576                   // NN*MAXD ints   = 16 MB
#define WS_ZA     (WS_ELL + NN * MAXD * 4)  // NN*32 f32      = 8 MB
#define WS_ZB     (WS_ZA + NN * 32 * 4)
#define WS_H1     (WS_ZB + NN * 32 * 4)
#define WS_H2     (WS_H1 + NN * 32 * 4)
#define WS_H3     (WS_H2 + NN * 32 * 4)
#define WS_Z4     (WS_H3 + NN * 32 * 4)     // NN f32

// ---------------------------------------------------------------------------
// Build ELL adjacency rows keyed by dst: ell[dst][slot] = src.  4 edges/thread.
__global__ __launch_bounds__(256) void k_build(const int* __restrict__ ei,
                                               int* __restrict__ cursor,
                                               int* __restrict__ ell) {
    int idx = blockIdx.x * 256 + threadIdx.x;
    const int4* e4 = (const int4*)ei;
    int4 s = e4[idx];
    int4 d = e4[NE / 4 + idx];
    int t;
    t = atomicAdd(&cursor[d.x], 1); if (t < MAXD) ell[d.x * MAXD + t] = s.x;
    t = atomicAdd(&cursor[d.y], 1); if (t < MAXD) ell[d.y * MAXD + t] = s.y;
    t = atomicAdd(&cursor[d.z], 1); if (t < MAXD) ell[d.z * MAXD + t] = s.z;
    t = atomicAdd(&cursor[d.w], 1); if (t < MAXD) ell[d.w * MAXD + t] = s.w;
}

// ---------------------------------------------------------------------------
// z1 = feat (N x 128) @ W0 (128 x 32).  64 rows/block, thread = 4 rows x 2 cols.
__global__ __launch_bounds__(256) void k_gemm1(const float* __restrict__ feat,
                                               const float* __restrict__ W0,
                                               float* __restrict__ z1) {
    __shared__ float wl[32 * 132];   // W transposed: wl[c][k], stride 132
    __shared__ float hl[64 * 132];   // feat rows: hl[r][k], stride 132
    int tid = threadIdx.x;
    for (int i = tid; i < 128 * 32; i += 256) {
        int k = i >> 5, c = i & 31;
        wl[c * 132 + k] = W0[i];
    }
    int base = blockIdx.x * 64;
    const float* fsrc = feat + (size_t)base * 128;
    #pragma unroll
    for (int v = 0; v < 8; ++v) {
        int flat = v * 1024 + tid * 4;
        int rr = flat >> 7, kk = flat & 127;
        *(float4*)&hl[rr * 132 + kk] = *(const float4*)&fsrc[flat];
    }
    __syncthreads();
    int cg = tid & 15, rg = tid >> 4;
    int c0 = cg * 2, r0 = rg * 4;
    float acc[4][2] = {};
    #pragma unroll 2
    for (int k = 0; k < 128; k += 4) {
        float4 wa = *(const float4*)&wl[c0 * 132 + k];
        float4 wb = *(const float4*)&wl[(c0 + 1) * 132 + k];
        #pragma unroll
        for (int rr = 0; rr < 4; ++rr) {
            float4 hv = *(const float4*)&hl[(r0 + rr) * 132 + k];
            acc[rr][0] += hv.x * wa.x + hv.y * wa.y + hv.z * wa.z + hv.w * wa.w;
            acc[rr][1] += hv.x * wb.x + hv.y * wb.y + hv.z * wb.z + hv.w * wb.w;
        }
    }
    #pragma unroll
    for (int rr = 0; rr < 4; ++rr) {
        int d = base + r0 + rr;
        z1[d * 32 + c0]     = acc[rr][0];
        z1[d * 32 + c0 + 1] = acc[rr][1];
    }
}

// ---------------------------------------------------------------------------
// Gather helper: acc over neighbors with 8-deep load batching (ILP).
__device__ __forceinline__ float gather32(const int* __restrict__ row, int cnt,
                                          const float* __restrict__ zin, int c) {
    int i0 = row[c];
    float acc = 0.f;
    int m = cnt < 32 ? cnt : 32;
    int j = 0;
    for (; j + 8 <= m; j += 8) {
        int s0 = __shfl(i0, j, 32),     s1 = __shfl(i0, j + 1, 32);
        int s2 = __shfl(i0, j + 2, 32), s3 = __shfl(i0, j + 3, 32);
        int s4 = __shfl(i0, j + 4, 32), s5 = __shfl(i0, j + 5, 32);
        int s6 = __shfl(i0, j + 6, 32), s7 = __shfl(i0, j + 7, 32);
        float t0 = zin[s0 * 32 + c], t1 = zin[s1 * 32 + c];
        float t2 = zin[s2 * 32 + c], t3 = zin[s3 * 32 + c];
        float t4 = zin[s4 * 32 + c], t5 = zin[s5 * 32 + c];
        float t6 = zin[s6 * 32 + c], t7 = zin[s7 * 32 + c];
        acc += ((t0 + t1) + (t2 + t3)) + ((t4 + t5) + (t6 + t7));
    }
    for (; j + 2 <= m; j += 2) {
        int s0 = __shfl(i0, j, 32), s1 = __shfl(i0, j + 1, 32);
        float t0 = zin[s0 * 32 + c], t1 = zin[s1 * 32 + c];
        acc += t0 + t1;
    }
    for (; j < m; ++j) acc += zin[__shfl(i0, j, 32) * 32 + c];
    if (cnt > 32) {   // rare (P ~ 1e-4 per node)
        int i1 = row[32 + c];
        for (int j2 = 32; j2 < cnt; ++j2)
            acc += zin[__shfl(i1, j2 - 32, 32) * 32 + c];
    }
    return acc;
}

// ---------------------------------------------------------------------------
// Fused: agg = A*zin;  h = tanh((agg + zin + b)/deg);  znext = h @ Wn (32x32)
__global__ __launch_bounds__(256) void k_layer(const int* __restrict__ cursor,
                                               const int* __restrict__ ell,
                                               const float* __restrict__ zin,
                                               const float* __restrict__ degs,
                                               const float* __restrict__ bias,
                                               const float* __restrict__ Wn,
                                               float* __restrict__ hout,
                                               float* __restrict__ znext) {
    __shared__ float wt[32 * 36];    // W transposed: wt[c][k], stride 36 (16B aligned)
    __shared__ float hl[8][36];
    int tid = threadIdx.x;
    for (int i = tid; i < 1024; i += 256) {
        int k = i >> 5, c = i & 31;
        wt[c * 36 + k] = Wn[i];
    }
    int r = tid >> 5, c = tid & 31;
    int d = blockIdx.x * 8 + r;
    int cnt = cursor[d]; if (cnt > MAXD) cnt = MAXD;
    const int* row = ell + (size_t)d * MAXD;
    float acc = gather32(row, cnt, zin, c);
    float val = tanhf((acc + zin[d * 32 + c] + bias[c]) / degs[d]);
    hout[d * 32 + c] = val;
    hl[r][c] = val;
    __syncthreads();
    const float* hrow = &hl[r][0];
    const float* wrow = wt + c * 36;
    float4 a4 = {0.f, 0.f, 0.f, 0.f};
    #pragma unroll
    for (int k = 0; k < 32; k += 4) {
        float4 hv = *(const float4*)&hrow[k];
        float4 wv = *(const float4*)&wrow[k];
        a4.x += hv.x * wv.x; a4.y += hv.y * wv.y;
        a4.z += hv.z * wv.z; a4.w += hv.w * wv.w;
    }
    znext[d * 32 + c] = (a4.x + a4.y) + (a4.z + a4.w);
}

// ---------------------------------------------------------------------------
// Layer 3 variant: znext is 1-wide (z4 = h3 @ W3), done with a shuffle reduce.
__global__ __launch_bounds__(256) void k_layer3(const int* __restrict__ cursor,
                                                const int* __restrict__ ell,
                                                const float* __restrict__ zin,
                                                const float* __restrict__ degs,
                                                const float* __restrict__ bias,
                                                const float* __restrict__ W3,
                                                float* __restrict__ hout,
                                                float* __restrict__ z4) {
    int tid = threadIdx.x;
    int r = tid >> 5, c = tid & 31;
    int d = blockIdx.x * 8 + r;
    int cnt = cursor[d]; if (cnt > MAXD) cnt = MAXD;
    const int* row = ell + (size_t)d * MAXD;
    float acc = gather32(row, cnt, zin, c);
    float val = tanhf((acc + zin[d * 32 + c] + bias[c]) / degs[d]);
    hout[d * 32 + c] = val;
    float v = val * W3[c];
    #pragma unroll
    for (int off = 16; off; off >>= 1) v += __shfl_xor(v, off, 32);
    if (c == 0) z4[d] = v;
}

// ---------------------------------------------------------------------------
// Fused: layer-4 gather (1-wide) -> h4; msg=[h1 h2 h3 h4]; phi=relu(msg@phiW+b);
// per-graph partial sum -> one atomicAdd set per block.
__global__ __launch_bounds__(256) void k_phi(const int* __restrict__ cursor,
                                             const int* __restrict__ ell,
                                             const float* __restrict__ z4,
                                             const float* __restrict__ degs,
                                             const float* __restrict__ b3,
                                             const float* __restrict__ h1,
                                             const float* __restrict__ h2,
                                             const float* __restrict__ h3,
                                             const float* __restrict__ phiW,
                                             const float* __restrict__ phib,
                                             float* __restrict__ summed) {
    __shared__ float pl[30 * 100];   // phiW transposed: pl[c][j], stride 100 (16B aligned)
    __shared__ float ml[8 * 100];    // msg rows, stride 100
    __shared__ float part[4][32];
    int tid = threadIdx.x;
    for (int i = tid; i < 30 * 97; i += 256) {
        int cc = i / 97, jj = i - cc * 97;
        pl[cc * 100 + jj] = phiW[jj * 30 + cc];
    }
    int r = tid >> 5, c = tid & 31;
    int d = blockIdx.x * 8 + r;
    int g = d >> 11;
    int cnt = cursor[d]; if (cnt > MAXD) cnt = MAXD;
    const int* row = ell + (size_t)d * MAXD;
    float acc = 0.f;
    for (int j = c; j < cnt; j += 32) acc += z4[row[j]];
    #pragma unroll
    for (int off = 16; off; off >>= 1) acc += __shfl_xor(acc, off, 32);
    float h4 = tanhf((acc + z4[d] + b3[0]) / degs[d]);   // uniform across the 32-lane group
    ml[r * 100 + c]      = h1[d * 32 + c];
    ml[r * 100 + 32 + c] = h2[d * 32 + c];
    ml[r * 100 + 64 + c] = h3[d * 32 + c];
    if (c == 0) ml[r * 100 + 96] = h4;
    __syncthreads();
    float s = 0.f;
    if (c < 30) {
        const float* mrow = ml + r * 100;
        const float* prow = pl + c * 100;
        float4 a4 = {0.f, 0.f, 0.f, 0.f};
        #pragma unroll
        for (int j = 0; j < 96; j += 4) {
            float4 mv = *(const float4*)&mrow[j];
            float4 pv = *(const float4*)&prow[j];
            a4.x += mv.x * pv.x; a4.y += mv.y * pv.y;
            a4.z += mv.z * pv.z; a4.w += mv.w * pv.w;
        }
        s = (a4.x + a4.y) + (a4.z + a4.w) + mrow[96] * prow[96] + phib[c];
        s = fmaxf(s, 0.f);
    }
    s += __shfl_down(s, 32);                 // rows pair-summed within each wave
    int wave = tid >> 6;
    if ((tid & 63) < 32) part[wave][tid & 31] = s;
    __syncthreads();
    if (tid < 32) {
        float tot = part[0][tid] + part[1][tid] + part[2][tid] + part[3][tid];
        if (tid < 30) atomicAdd(&summed[g * 30 + tid], tot);
    }
}

// ---------------------------------------------------------------------------
// out = summed @ rhoW + rhob   (32x30 @ 30x32)
__global__ __launch_bounds__(1024) void k_rho(const float* __restrict__ summed,
                                              const float* __restrict__ rhoW,
                                              const float* __restrict__ rhob,
                                              float* __restrict__ out) {
    int tid = threadIdx.x;
    int b = tid >> 5, o = tid & 31;
    float s = rhob[o];
    #pragma unroll
    for (int k = 0; k < 30; ++k) s += summed[b * 30 + k] * rhoW[k * 32 + o];
    out[tid] = s;
}

// ---------------------------------------------------------------------------
extern "C" void kernel_launch(void* const* d_in, const int* in_sizes, int n_in,
                              void* d_out, int out_size, void* d_ws, size_t ws_size,
                              hipStream_t stream) {
    const float* feat = (const float*)d_in[0];
    const float* degs = (const float*)d_in[1];
    const int*   ei   = (const int*)d_in[2];
    const float* W0   = (const float*)d_in[3];
    const float* b0   = (const float*)d_in[4];
    const float* W1   = (const float*)d_in[5];
    const float* b1   = (const float*)d_in[6];
    const float* W2   = (const float*)d_in[7];
    const float* b2   = (const float*)d_in[8];
    const float* W3   = (const float*)d_in[9];
    const float* b3   = (const float*)d_in[10];
    const float* phiW = (const float*)d_in[11];
    const float* phib = (const float*)d_in[12];
    const float* rhoW = (const float*)d_in[13];
    const float* rhob = (const float*)d_in[14];

    char* ws = (char*)d_ws;
    int*   cursor = (int*)(ws + WS_CURSOR);
    float* summed = (float*)(ws + WS_SUMMED);
    int*   ell    = (int*)(ws + WS_ELL);
    float* za     = (float*)(ws + WS_ZA);
    float* zb     = (float*)(ws + WS_ZB);
    float* h1     = (float*)(ws + WS_H1);
    float* h2     = (float*)(ws + WS_H2);
    float* h3     = (float*)(ws + WS_H3);
    float* z4     = (float*)(ws + WS_Z4);
    float* out    = (float*)d_out;

    // zero cursor + summed (ws is poisoned to 0xAA before every launch)
    hipMemsetAsync(ws, 0, WS_SUMMED + NG * 30 * 4, stream);

    k_build <<<NE / 1024, 256, 0, stream>>>(ei, cursor, ell);
    k_gemm1 <<<NN / 64, 256, 0, stream>>>(feat, W0, za);
    k_layer <<<NN / 8, 256, 0, stream>>>(cursor, ell, za, degs, b0, W1, h1, zb);
    k_layer <<<NN / 8, 256, 0, stream>>>(cursor, ell, zb, degs, b1, W2, h2, za);
    k_layer3<<<NN / 8, 256, 0, stream>>>(cursor, ell, za, degs, b2, W3, h3, z4);
    k_phi   <<<NN / 8, 256, 0, stream>>>(cursor, ell, z4, degs, b3, h1, h2, h3, phiW, phib, summed);
    k_rho   <<<1, 1024, 0, stream>>>(summed, rhoW, rhob, out);
}

// Round 3
// 263.081 us; speedup vs baseline: 1.2889x; 1.1204x over previous
//
#include <hip/hip_runtime.h>
#include <hip/hip_bf16.h>

// Problem constants (fixed by the reference harness)
#define NN 65536            // total nodes
#define NE (NN * 16)        // total edges = 1,048,576
#define NG 32               // graphs
#define MAXD 64             // ELL slots per node (max in-degree ~45 for Poisson(16))

// Workspace layout (bytes)
#define WS_CURSOR 0                         // NN ints        = 262144
#define WS_SUMMED 262144                    // NG*30 floats   = 3840
#define WS_ELL    1048576                   // NN*MAXD ints   = 16 MB
#define WS_ZA     (WS_ELL + NN * MAXD * 4)  // NN*32 f32      = 8 MB
#define WS_ZB     (WS_ZA + NN * 32 * 4)
#define WS_H1     (WS_ZB + NN * 32 * 4)
#define WS_H2     (WS_H1 + NN * 32 * 4)
#define WS_H3     (WS_H2 + NN * 32 * 4)
#define WS_Z4     (WS_H3 + NN * 32 * 4)     // NN f32

// XCD-affine swizzle: 8 XCDs, round-robin dispatch assumed (blockIdx % 8).
// Gives XCD x the contiguous original-block range [x*chunk, (x+1)*chunk),
// i.e. 4 graphs per XCD -> per-XCD L2 footprint ~2 MB instead of 16 MB.
__device__ __forceinline__ int xcd_swz(int b, int chunk) {
    return (b & 7) * chunk + (b >> 3);
}

// ---------------------------------------------------------------------------
// Build ELL adjacency rows keyed by dst: ell[dst][slot] = src.  4 edges/thread.
__global__ __launch_bounds__(256) void k_build(const int* __restrict__ ei,
                                               int* __restrict__ cursor,
                                               int* __restrict__ ell) {
    int blk = xcd_swz(blockIdx.x, NE / 1024 / 8);   // 1024 blocks -> chunk 128
    int idx = blk * 256 + threadIdx.x;
    const int4* e4 = (const int4*)ei;
    int4 s = e4[idx];
    int4 d = e4[NE / 4 + idx];
    int t;
    t = atomicAdd(&cursor[d.x], 1); if (t < MAXD) ell[d.x * MAXD + t] = s.x;
    t = atomicAdd(&cursor[d.y], 1); if (t < MAXD) ell[d.y * MAXD + t] = s.y;
    t = atomicAdd(&cursor[d.z], 1); if (t < MAXD) ell[d.z * MAXD + t] = s.z;
    t = atomicAdd(&cursor[d.w], 1); if (t < MAXD) ell[d.w * MAXD + t] = s.w;
}

// ---------------------------------------------------------------------------
// z1 = feat (N x 128) @ W0 (128 x 32).  64 rows/block, thread = 4 rows x 2 cols.
__global__ __launch_bounds__(256) void k_gemm1(const float* __restrict__ feat,
                                               const float* __restrict__ W0,
                                               float* __restrict__ z1) {
    __shared__ float wl[32 * 132];   // W transposed: wl[c][k], stride 132
    __shared__ float hl[64 * 132];   // feat rows: hl[r][k], stride 132
    int tid = threadIdx.x;
    for (int i = tid; i < 128 * 32; i += 256) {
        int k = i >> 5, c = i & 31;
        wl[c * 132 + k] = W0[i];
    }
    int base = blockIdx.x * 64;
    const float* fsrc = feat + (size_t)base * 128;
    #pragma unroll
    for (int v = 0; v < 8; ++v) {
        int flat = v * 1024 + tid * 4;
        int rr = flat >> 7, kk = flat & 127;
        *(float4*)&hl[rr * 132 + kk] = *(const float4*)&fsrc[flat];
    }
    __syncthreads();
    int cg = tid & 15, rg = tid >> 4;
    int c0 = cg * 2, r0 = rg * 4;
    float acc[4][2] = {};
    #pragma unroll 2
    for (int k = 0; k < 128; k += 4) {
        float4 wa = *(const float4*)&wl[c0 * 132 + k];
        float4 wb = *(const float4*)&wl[(c0 + 1) * 132 + k];
        #pragma unroll
        for (int rr = 0; rr < 4; ++rr) {
            float4 hv = *(const float4*)&hl[(r0 + rr) * 132 + k];
            acc[rr][0] += hv.x * wa.x + hv.y * wa.y + hv.z * wa.z + hv.w * wa.w;
            acc[rr][1] += hv.x * wb.x + hv.y * wb.y + hv.z * wb.z + hv.w * wb.w;
        }
    }
    #pragma unroll
    for (int rr = 0; rr < 4; ++rr) {
        int d = base + r0 + rr;
        z1[d * 32 + c0]     = acc[rr][0];
        z1[d * 32 + c0 + 1] = acc[rr][1];
    }
}

// ---------------------------------------------------------------------------
// Gather helper: acc over neighbors with 8-deep load batching (ILP).
__device__ __forceinline__ float gather32(const int* __restrict__ row, int cnt,
                                          const float* __restrict__ zin, int c) {
    int i0 = row[c];
    float acc = 0.f;
    int m = cnt < 32 ? cnt : 32;
    int j = 0;
    for (; j + 8 <= m; j += 8) {
        int s0 = __shfl(i0, j, 32),     s1 = __shfl(i0, j + 1, 32);
        int s2 = __shfl(i0, j + 2, 32), s3 = __shfl(i0, j + 3, 32);
        int s4 = __shfl(i0, j + 4, 32), s5 = __shfl(i0, j + 5, 32);
        int s6 = __shfl(i0, j + 6, 32), s7 = __shfl(i0, j + 7, 32);
        float t0 = zin[s0 * 32 + c], t1 = zin[s1 * 32 + c];
        float t2 = zin[s2 * 32 + c], t3 = zin[s3 * 32 + c];
        float t4 = zin[s4 * 32 + c], t5 = zin[s5 * 32 + c];
        float t6 = zin[s6 * 32 + c], t7 = zin[s7 * 32 + c];
        acc += ((t0 + t1) + (t2 + t3)) + ((t4 + t5) + (t6 + t7));
    }
    for (; j + 2 <= m; j += 2) {
        int s0 = __shfl(i0, j, 32), s1 = __shfl(i0, j + 1, 32);
        float t0 = zin[s0 * 32 + c], t1 = zin[s1 * 32 + c];
        acc += t0 + t1;
    }
    for (; j < m; ++j) acc += zin[__shfl(i0, j, 32) * 32 + c];
    if (cnt > 32) {   // rare (P ~ 1e-4 per node)
        int i1 = row[32 + c];
        for (int j2 = 32; j2 < cnt; ++j2)
            acc += zin[__shfl(i1, j2 - 32, 32) * 32 + c];
    }
    return acc;
}

// ---------------------------------------------------------------------------
// Fused: agg = A*zin;  h = tanh((agg + zin + b)/deg);  znext = h @ Wn (32x32)
__global__ __launch_bounds__(256) void k_layer(const int* __restrict__ cursor,
                                               const int* __restrict__ ell,
                                               const float* __restrict__ zin,
                                               const float* __restrict__ degs,
                                               const float* __restrict__ bias,
                                               const float* __restrict__ Wn,
                                               float* __restrict__ hout,
                                               float* __restrict__ znext) {
    __shared__ float wt[32 * 36];    // W transposed: wt[c][k], stride 36 (16B aligned)
    __shared__ float hl[8][36];
    int tid = threadIdx.x;
    for (int i = tid; i < 1024; i += 256) {
        int k = i >> 5, c = i & 31;
        wt[c * 36 + k] = Wn[i];
    }
    int blk = xcd_swz(blockIdx.x, NN / 8 / 8);      // 8192 blocks -> chunk 1024
    int r = tid >> 5, c = tid & 31;
    int d = blk * 8 + r;
    int cnt = cursor[d]; if (cnt > MAXD) cnt = MAXD;
    const int* row = ell + (size_t)d * MAXD;
    float acc = gather32(row, cnt, zin, c);
    float val = tanhf((acc + zin[d * 32 + c] + bias[c]) / degs[d]);
    hout[d * 32 + c] = val;
    hl[r][c] = val;
    __syncthreads();
    const float* hrow = &hl[r][0];
    const float* wrow = wt + c * 36;
    float4 a4 = {0.f, 0.f, 0.f, 0.f};
    #pragma unroll
    for (int k = 0; k < 32; k += 4) {
        float4 hv = *(const float4*)&hrow[k];
        float4 wv = *(const float4*)&wrow[k];
        a4.x += hv.x * wv.x; a4.y += hv.y * wv.y;
        a4.z += hv.z * wv.z; a4.w += hv.w * wv.w;
    }
    znext[d * 32 + c] = (a4.x + a4.y) + (a4.z + a4.w);
}

// ---------------------------------------------------------------------------
// Layer 3 variant: znext is 1-wide (z4 = h3 @ W3), done with a shuffle reduce.
__global__ __launch_bounds__(256) void k_layer3(const int* __restrict__ cursor,
                                                const int* __restrict__ ell,
                                                const float* __restrict__ zin,
                                                const float* __restrict__ degs,
                                                const float* __restrict__ bias,
                                                const float* __restrict__ W3,
                                                float* __restrict__ hout,
                                                float* __restrict__ z4) {
    int tid = threadIdx.x;
    int blk = xcd_swz(blockIdx.x, NN / 8 / 8);
    int r = tid >> 5, c = tid & 31;
    int d = blk * 8 + r;
    int cnt = cursor[d]; if (cnt > MAXD) cnt = MAXD;
    const int* row = ell + (size_t)d * MAXD;
    float acc = gather32(row, cnt, zin, c);
    float val = tanhf((acc + zin[d * 32 + c] + bias[c]) / degs[d]);
    hout[d * 32 + c] = val;
    float v = val * W3[c];
    #pragma unroll
    for (int off = 16; off; off >>= 1) v += __shfl_xor(v, off, 32);
    if (c == 0) z4[d] = v;
}

// ---------------------------------------------------------------------------
// Fused: layer-4 gather (1-wide) -> h4; msg=[h1 h2 h3 h4]; phi=relu(msg@phiW+b);
// per-graph partial sum -> one atomicAdd set per block.
__global__ __launch_bounds__(256) void k_phi(const int* __restrict__ cursor,
                                             const int* __restrict__ ell,
                                             const float* __restrict__ z4,
                                             const float* __restrict__ degs,
                                             const float* __restrict__ b3,
                                             const float* __restrict__ h1,
                                             const float* __restrict__ h2,
                                             const float* __restrict__ h3,
                                             const float* __restrict__ phiW,
                                             const float* __restrict__ phib,
                                             float* __restrict__ summed) {
    __shared__ float pl[30 * 100];   // phiW transposed: pl[c][j], stride 100 (16B aligned)
    __shared__ float ml[8 * 100];    // msg rows, stride 100
    __shared__ float part[4][32];
    int tid = threadIdx.x;
    for (int i = tid; i < 30 * 97; i += 256) {
        int cc = i / 97, jj = i - cc * 97;
        pl[cc * 100 + jj] = phiW[jj * 30 + cc];
    }
    int blk = xcd_swz(blockIdx.x, NN / 8 / 8);
    int r = tid >> 5, c = tid & 31;
    int d = blk * 8 + r;
    int g = d >> 11;
    int cnt = cursor[d]; if (cnt > MAXD) cnt = MAXD;
    const int* row = ell + (size_t)d * MAXD;
    float acc = 0.f;
    for (int j = c; j < cnt; j += 32) acc += z4[row[j]];
    #pragma unroll
    for (int off = 16; off; off >>= 1) acc += __shfl_xor(acc, off, 32);
    float h4 = tanhf((acc + z4[d] + b3[0]) / degs[d]);   // uniform across the 32-lane group
    ml[r * 100 + c]      = h1[d * 32 + c];
    ml[r * 100 + 32 + c] = h2[d * 32 + c];
    ml[r * 100 + 64 + c] = h3[d * 32 + c];
    if (c == 0) ml[r * 100 + 96] = h4;
    __syncthreads();
    float s = 0.f;
    if (c < 30) {
        const float* mrow = ml + r * 100;
        const float* prow = pl + c * 100;
        float4 a4 = {0.f, 0.f, 0.f, 0.f};
        #pragma unroll
        for (int j = 0; j < 96; j += 4) {
            float4 mv = *(const float4*)&mrow[j];
            float4 pv = *(const float4*)&prow[j];
            a4.x += mv.x * pv.x; a4.y += mv.y * pv.y;
            a4.z += mv.z * pv.z; a4.w += mv.w * pv.w;
        }
        s = (a4.x + a4.y) + (a4.z + a4.w) + mrow[96] * prow[96] + phib[c];
        s = fmaxf(s, 0.f);
    }
    s += __shfl_down(s, 32);                 // rows pair-summed within each wave
    int wave = tid >> 6;
    if ((tid & 63) < 32) part[wave][tid & 31] = s;
    __syncthreads();
    if (tid < 32) {
        float tot = part[0][tid] + part[1][tid] + part[2][tid] + part[3][tid];
        if (tid < 30) atomicAdd(&summed[g * 30 + tid], tot);
    }
}

// ---------------------------------------------------------------------------
// out = summed @ rhoW + rhob   (32x30 @ 30x32)
__global__ __launch_bounds__(1024) void k_rho(const float* __restrict__ summed,
                                              const float* __restrict__ rhoW,
                                              const float* __restrict__ rhob,
                                              float* __restrict__ out) {
    int tid = threadIdx.x;
    int b = tid >> 5, o = tid & 31;
    float s = rhob[o];
    #pragma unroll
    for (int k = 0; k < 30; ++k) s += summed[b * 30 + k] * rhoW[k * 32 + o];
    out[tid] = s;
}

// ---------------------------------------------------------------------------
extern "C" void kernel_launch(void* const* d_in, const int* in_sizes, int n_in,
                              void* d_out, int out_size, void* d_ws, size_t ws_size,
                              hipStream_t stream) {
    const float* feat = (const float*)d_in[0];
    const float* degs = (const float*)d_in[1];
    const int*   ei   = (const int*)d_in[2];
    const float* W0   = (const float*)d_in[3];
    const float* b0   = (const float*)d_in[4];
    const float* W1   = (const float*)d_in[5];
    const float* b1   = (const float*)d_in[6];
    const float* W2   = (const float*)d_in[7];
    const float* b2   = (const float*)d_in[8];
    const float* W3   = (const float*)d_in[9];
    const float* b3   = (const float*)d_in[10];
    const float* phiW = (const float*)d_in[11];
    const float* phib = (const float*)d_in[12];
    const float* rhoW = (const float*)d_in[13];
    const float* rhob = (const float*)d_in[14];

    char* ws = (char*)d_ws;
    int*   cursor = (int*)(ws + WS_CURSOR);
    float* summed = (float*)(ws + WS_SUMMED);
    int*   ell    = (int*)(ws + WS_ELL);
    float* za     = (float*)(ws + WS_ZA);
    float* zb     = (float*)(ws + WS_ZB);
    float* h1     = (float*)(ws + WS_H1);
    float* h2     = (float*)(ws + WS_H2);
    float* h3     = (float*)(ws + WS_H3);
    float* z4     = (float*)(ws + WS_Z4);
    float* out    = (float*)d_out;

    // zero cursor + summed (ws is poisoned to 0xAA before every launch)
    hipMemsetAsync(ws, 0, WS_SUMMED + NG * 30 * 4, stream);

    k_build <<<NE / 1024, 256, 0, stream>>>(ei, cursor, ell);
    k_gemm1 <<<NN / 64, 256, 0, stream>>>(feat, W0, za);
    k_layer <<<NN / 8, 256, 0, stream>>>(cursor, ell, za, degs, b0, W1, h1, zb);
    k_layer <<<NN / 8, 256, 0, stream>>>(cursor, ell, zb, degs, b1, W2, h2, za);
    k_layer3<<<NN / 8, 256, 0, stream>>>(cursor, ell, za, degs, b2, W3, h3, z4);
    k_phi   <<<NN / 8, 256, 0, stream>>>(cursor, ell, z4, degs, b3, h1, h2, h3, phiW, phib, summed);
    k_rho   <<<1, 1024, 0, stream>>>(summed, rhoW, rhob, out);
}